// Round 7
// baseline (215.249 us; speedup 1.0000x reference)
//
#include <hip/hip_runtime.h>

#define BATCH 32768
#define SEQ 512
#define TPL 8          // timesteps per lane (64 lanes * 8 = 512)
#define EPS 1e-8f

typedef float floatx4 __attribute__((ext_vector_type(4)));

// v8 = v7 + NON-TEMPORAL STORES on `out`. Single-variable A/B vs v7.
//
// r6 evidence: nt-load on values cut dur 86->72us at CONSTANT fetch bytes ->
// the lever is cache-allocation politics, not byte count. values lines no
// longer compete for L2/LLC ways. Remaining self-inflicted pollution: our
// 67MB/iter write-allocating out stores. With both zero-reuse streams (values
// reads, out writes) marked nt, cache capacity concentrates on rewards+dones
// (134MB; +poisoned out region ~= 201MB < 256MiB) -> r/d cache-resident across
// graph-replay iterations. v5b proved nt-stores are costless standalone
// (WRITE 65.5->72MB, dur unchanged); v7 created the residency state they
// protect. Prereq-gated combo.
__global__ void __launch_bounds__(256)
glr_wave_scan8(const float* __restrict__ values,
               const float* __restrict__ rewards,
               const float* __restrict__ dones,
               const float* __restrict__ raw_gamma,
               const float* __restrict__ raw_lambd,
               float* __restrict__ out) {
    const int lane = threadIdx.x & 63;
    const int wv   = threadIdx.x >> 6;
    const int row  = blockIdx.x * 4 + wv;
    const int t0   = lane * TPL;

    const float* __restrict__ vrow = values  + (size_t)row * (SEQ + 1);
    const float* __restrict__ rrow = rewards + (size_t)row * SEQ + t0;
    const float* __restrict__ drow = dones   + (size_t)row * SEQ + t0;
    float*       __restrict__ orow = out     + (size_t)row * SEQ + t0;

    // ---- issue ALL independent global loads up front (all dwordx4) ----
    // values: non-temporal (evict-first) -> doesn't displace r/d in cache
    const floatx4 v4a = __builtin_nontemporal_load((const floatx4*)(vrow + t0));
    const floatx4 v4b = __builtin_nontemporal_load((const floatx4*)(vrow + t0 + 4));
    const float4 r4a = *(const float4*)(rrow);
    const float4 r4b = *(const float4*)(rrow + 4);
    const float4 d4a = *(const float4*)(drow);
    const float4 d4b = *(const float4*)(drow + 4);
    const float4 l4a = *(const float4*)(raw_lambd + t0);
    const float4 l4b = *(const float4*)(raw_lambd + t0 + 4);
    const float vlast = __builtin_nontemporal_load(vrow + SEQ);  // wave-uniform

    const float gamma = fmaxf(tanhf(raw_gamma[0]), EPS);

    // vj[j] = vrow[1 + t0 + j]: shift the aligned pair left by one element,
    // pulling element 8 from the next lane. Lane 63: vrow[512] == vlast.
    const float nx = __shfl_down(v4a.x, 1, 64);
    float vj[TPL] = {v4a.y, v4a.z, v4a.w, v4b.x, v4b.y, v4b.z, v4b.w,
                     (lane == 63) ? vlast : nx};

    float rj[TPL] = {r4a.x, r4a.y, r4a.z, r4a.w, r4b.x, r4b.y, r4b.z, r4b.w};
    float dj[TPL] = {d4a.x, d4a.y, d4a.z, d4a.w, d4b.x, d4b.y, d4b.z, d4b.w};
    const float lr[TPL] = {l4a.x, l4a.y, l4a.z, l4a.w, l4b.x, l4b.y, l4b.z, l4b.w};
    float lm[TPL];
    #pragma unroll
    for (int j = 0; j < TPL; ++j)
        lm[j] = fmaxf(tanhf(lr[j]), EPS);

    // ---- per-lane affine summary (t descending) ----
    float a[TPL], b[TPL];
    float A = 1.f, Bv = 0.f;
    #pragma unroll
    for (int j = TPL - 1; j >= 0; --j) {
        const float g = gamma * (1.f - dj[j]);
        a[j] = g * lm[j];
        b[j] = fmaf(g * (1.f - lm[j]), vj[j], rj[j]);
        Bv = fmaf(a[j], Bv, b[j]);
        A  = a[j] * A;
    }

    // ---- wave-level inclusive suffix scan of (A,B) ----
    #pragma unroll
    for (int dlt = 1; dlt < 64; dlt <<= 1) {
        const float oA = __shfl_down(A, dlt, 64);
        const float oB = __shfl_down(Bv, dlt, 64);
        if (lane + dlt < 64) {                // compose(mine, downstream)
            Bv = fmaf(A, oB, Bv);
            A  = A * oA;
        }
    }
    float EA = __shfl_down(A, 1, 64);
    float EB = __shfl_down(Bv, 1, 64);
    if (lane == 63) { EA = 1.f; EB = 0.f; }

    // ret at this lane's right boundary; values[row][SEQ] is the scan init
    float ret = fmaf(EA, vlast, EB);

    // ---- replay, emit outputs (nt: write-only stream, keep out of cache) ----
    float o[TPL];
    #pragma unroll
    for (int j = TPL - 1; j >= 0; --j) {
        ret = fmaf(a[j], ret, b[j]);
        o[j] = ret;
    }
    floatx4 o0 = {o[0], o[1], o[2], o[3]};
    floatx4 o1 = {o[4], o[5], o[6], o[7]};
    __builtin_nontemporal_store(o0, (floatx4*)(orow));
    __builtin_nontemporal_store(o1, (floatx4*)(orow + 4));
}

extern "C" void kernel_launch(void* const* d_in, const int* in_sizes, int n_in,
                              void* d_out, int out_size, void* d_ws, size_t ws_size,
                              hipStream_t stream) {
    const float* values    = (const float*)d_in[0];
    const float* rewards   = (const float*)d_in[1];
    const float* dones     = (const float*)d_in[2];
    const float* raw_gamma = (const float*)d_in[3];
    const float* raw_lambd = (const float*)d_in[4];
    float* out = (float*)d_out;

    const int block = 256;                 // 4 waves = 4 rows per block
    const int grid = BATCH / 4;            // 8192 blocks
    glr_wave_scan8<<<grid, block, 0, stream>>>(
        values, rewards, dones, raw_gamma, raw_lambd, out);
}

// Round 8
// 209.461 us; speedup vs baseline: 1.0276x; 1.0276x over previous
//
#include <hip/hip_runtime.h>

#define BATCH 32768
#define SEQ 512
#define TPL 8          // timesteps per lane (64 lanes * 8 = 512)
#define EPS 1e-8f

typedef float floatx4 __attribute__((ext_vector_type(4)));

// v9 = v7 + NON-TEMPORAL loads on rewards+dones (stores back to NORMAL;
// v8 falsified nt-stores: neutral dur, +7MB HBM writes).
//
// Model after r0-r7: service-rate-bound. v7's mixed regime: 101MB LLC-hit
// + 100MB miss reads + 66MB writes served at only 2.4 TB/s; waves queue
// ~90% of their lifetime (retire interval 1200cy/CU at 22 resident waves).
// Pure-stream ceiling is 6.3 TB/s (m13). This probe converts ALL reads to
// non-allocating sequential streams: HBM sees 201MB R + 66MB W of pure
// streams. If stream rate >=5 TB/s, 267MB -> <=55us beats v7's 72us despite
// 2x bytes. Decisive either way: regression means LLC hits were load-bearing
// and v7 is the floor.
__global__ void __launch_bounds__(256)
glr_wave_scan9(const float* __restrict__ values,
               const float* __restrict__ rewards,
               const float* __restrict__ dones,
               const float* __restrict__ raw_gamma,
               const float* __restrict__ raw_lambd,
               float* __restrict__ out) {
    const int lane = threadIdx.x & 63;
    const int wv   = threadIdx.x >> 6;
    const int row  = blockIdx.x * 4 + wv;
    const int t0   = lane * TPL;

    const float* __restrict__ vrow = values  + (size_t)row * (SEQ + 1);
    const float* __restrict__ rrow = rewards + (size_t)row * SEQ + t0;
    const float* __restrict__ drow = dones   + (size_t)row * SEQ + t0;
    float*       __restrict__ orow = out     + (size_t)row * SEQ + t0;

    // ---- issue ALL independent global loads up front (all dwordx4, all nt) ----
    const floatx4 v4a = __builtin_nontemporal_load((const floatx4*)(vrow + t0));
    const floatx4 v4b = __builtin_nontemporal_load((const floatx4*)(vrow + t0 + 4));
    const floatx4 r4a = __builtin_nontemporal_load((const floatx4*)(rrow));
    const floatx4 r4b = __builtin_nontemporal_load((const floatx4*)(rrow + 4));
    const floatx4 d4a = __builtin_nontemporal_load((const floatx4*)(drow));
    const floatx4 d4b = __builtin_nontemporal_load((const floatx4*)(drow + 4));
    const float4 l4a = *(const float4*)(raw_lambd + t0);
    const float4 l4b = *(const float4*)(raw_lambd + t0 + 4);
    const float vlast = __builtin_nontemporal_load(vrow + SEQ);  // wave-uniform

    const float gamma = fmaxf(tanhf(raw_gamma[0]), EPS);

    // vj[j] = vrow[1 + t0 + j]: shift the aligned pair left by one element,
    // pulling element 8 from the next lane. Lane 63: vrow[512] == vlast.
    const float nx = __shfl_down(v4a.x, 1, 64);
    float vj[TPL] = {v4a.y, v4a.z, v4a.w, v4b.x, v4b.y, v4b.z, v4b.w,
                     (lane == 63) ? vlast : nx};

    float rj[TPL] = {r4a.x, r4a.y, r4a.z, r4a.w, r4b.x, r4b.y, r4b.z, r4b.w};
    float dj[TPL] = {d4a.x, d4a.y, d4a.z, d4a.w, d4b.x, d4b.y, d4b.z, d4b.w};
    const float lr[TPL] = {l4a.x, l4a.y, l4a.z, l4a.w, l4b.x, l4b.y, l4b.z, l4b.w};
    float lm[TPL];
    #pragma unroll
    for (int j = 0; j < TPL; ++j)
        lm[j] = fmaxf(tanhf(lr[j]), EPS);

    // ---- per-lane affine summary (t descending) ----
    float a[TPL], b[TPL];
    float A = 1.f, Bv = 0.f;
    #pragma unroll
    for (int j = TPL - 1; j >= 0; --j) {
        const float g = gamma * (1.f - dj[j]);
        a[j] = g * lm[j];
        b[j] = fmaf(g * (1.f - lm[j]), vj[j], rj[j]);
        Bv = fmaf(a[j], Bv, b[j]);
        A  = a[j] * A;
    }

    // ---- wave-level inclusive suffix scan of (A,B) ----
    #pragma unroll
    for (int dlt = 1; dlt < 64; dlt <<= 1) {
        const float oA = __shfl_down(A, dlt, 64);
        const float oB = __shfl_down(Bv, dlt, 64);
        if (lane + dlt < 64) {                // compose(mine, downstream)
            Bv = fmaf(A, oB, Bv);
            A  = A * oA;
        }
    }
    float EA = __shfl_down(A, 1, 64);
    float EB = __shfl_down(Bv, 1, 64);
    if (lane == 63) { EA = 1.f; EB = 0.f; }

    // ret at this lane's right boundary; values[row][SEQ] is the scan init
    float ret = fmaf(EA, vlast, EB);

    // ---- replay, emit outputs (normal stores; v8 falsified nt) ----
    float o[TPL];
    #pragma unroll
    for (int j = TPL - 1; j >= 0; --j) {
        ret = fmaf(a[j], ret, b[j]);
        o[j] = ret;
    }
    *(float4*)(orow)     = make_float4(o[0], o[1], o[2], o[3]);
    *(float4*)(orow + 4) = make_float4(o[4], o[5], o[6], o[7]);
}

extern "C" void kernel_launch(void* const* d_in, const int* in_sizes, int n_in,
                              void* d_out, int out_size, void* d_ws, size_t ws_size,
                              hipStream_t stream) {
    const float* values    = (const float*)d_in[0];
    const float* rewards   = (const float*)d_in[1];
    const float* dones     = (const float*)d_in[2];
    const float* raw_gamma = (const float*)d_in[3];
    const float* raw_lambd = (const float*)d_in[4];
    float* out = (float*)d_out;

    const int block = 256;                 // 4 waves = 4 rows per block
    const int grid = BATCH / 4;            // 8192 blocks
    glr_wave_scan9<<<grid, block, 0, stream>>>(
        values, rewards, dones, raw_gamma, raw_lambd, out);
}